// Round 5
// baseline (51.897 us; speedup 1.0000x reference)
//
#include <hip/hip_runtime.h>

#define N_PART 512
#define H_DIM 32
#define M_DIM 4
#define L_DIM 8
#define N_STEPS (M_DIM * (L_DIM - 1))   // 28
#define N_JOBS (N_STEPS + M_DIM)        // 32
#define NBLK (N_JOBS * 32)              // 1024 (32 rowgroups of 16 rows)
#define NCELL 2048
#define RMAX 10.0f
#define TSCALE ((float)NCELL / RMAX)    // 204.8
#define TWO_LOG2E 2.8853900817779268f

// ws layout:
//  [0, 24KB)      tab    float3[2048] {St,Sg,Sl} (12B stride: full bank spread)
//  [24KB, 32KB)   stTab  float[2048]  (packed St for EMODE's 8KB staging)
//  [32KB, +24)    acc    double[3]    (atomic accumulators: Jd, Lap, E)
//  [32KB+24, +4)  ticket unsigned
#define TAB_FLOATS (NCELL * 3)
#define TAB_BYTES (TAB_FLOATS * 4)
#define ST_OFF TAB_BYTES
#define ST_BYTES (NCELL * 4)
#define ACC_OFF (ST_OFF + ST_BYTES)
#define TICKET_OFF (ACC_OFF + 24)

// ---------------------------------------------------------------------------
// Build the r-tables: cell c holds {St, Sg, Sl} at r = c/TSCALE, plus a
// packed St-only copy for EMODE blocks' lighter staging. Block 0 also zeroes
// the atomic accumulators + ticket via RELAXED ATOMIC stores (coherence-point
// visible to main's atomics; plain stores could sit dirty in this XCD's L2
// while memory-side atomics read stale memory).
__global__ __launch_bounds__(256)
void tfl_tabgen(const float* __restrict__ p1, const float* __restrict__ pb1,
                const float* __restrict__ p2, float* __restrict__ tab,
                float* __restrict__ stTab, double* __restrict__ acc,
                unsigned* __restrict__ ticket) {
  if (blockIdx.x == 0 && threadIdx.x == 0) {
    __hip_atomic_store(&acc[0], 0.0, __ATOMIC_RELAXED, __HIP_MEMORY_SCOPE_AGENT);
    __hip_atomic_store(&acc[1], 0.0, __ATOMIC_RELAXED, __HIP_MEMORY_SCOPE_AGENT);
    __hip_atomic_store(&acc[2], 0.0, __ATOMIC_RELAXED, __HIP_MEMORY_SCOPE_AGENT);
    __hip_atomic_store(ticket, 0u, __ATOMIC_RELAXED, __HIP_MEMORY_SCOPE_AGENT);
  }
  const int c = blockIdx.x * 256 + threadIdx.x;
  if (c >= NCELL) return;
  const float r = (float)c * (RMAX / (float)NCELL);
  float St = 0.f, Sg = 0.f, Sl = 0.f;
  for (int h = 0; h < H_DIM; ++h) {
    float p1h = p1[h], P2h = p2[h];
    float arg = TWO_LOG2E * fmaf(r, p1h, pb1[h]);
    float y = __builtin_amdgcn_exp2f(arg);
    float u = __builtin_amdgcn_rcpf(y + 1.0f);
    float t = fmaf(-2.0f, u, 1.0f);            // tanh
    float dd = fmaf(-u, u, u);                 // sech^2 / 4
    St = fmaf(t, P2h, St);
    Sg = fmaf(dd, 4.0f * p1h * P2h, Sg);       // dPhi
    Sl = fmaf(t * dd, -8.0f * p1h * p1h * P2h, Sl);  // d2Phi
  }
  tab[3 * c + 0] = St;
  tab[3 * c + 1] = Sg;
  tab[3 * c + 2] = Sl;
  stTab[c] = St;
}

// ---------------------------------------------------------------------------
// Main: 1024 blocks = 32 jobs x 32 rowgroups(16 rows). 512 threads:
// 32 threads per row, each thread owns 16 j's. Single float3 table (12B
// stride -> gcd(3,32)=1 -> random gathers spread over all 32 banks).
// Mode-specialized READS (E telescoped): DRIFT / L0 / EMODE as round 4.
// Fused finalize v3 — ATOMICS ONLY, zero cache-maintenance:
//   - device-scope f64 atomicAdds execute at the memory-side coherence
//     point (bypass XCD L2) -> no fences needed (G12);
//   - s_waitcnt vmcnt(0) (raw, NOT a release) before the ticket bump
//     guarantees this block's adds committed first;
//   - winner (old == NBLK-1) reads sums with returning atomics, writes out.
// Round-1/3 lesson honored: no __threadfence, no release/acquire anywhere ->
// compiler cannot emit buffer_wbl2 / buffer_inv.
__global__ __launch_bounds__(512)
void tfl_main9(const float* __restrict__ data, const float* __restrict__ tsnap,
               const float* __restrict__ W1, const float* __restrict__ b1,
               const float* __restrict__ w2, const float* __restrict__ tab,
               const float* __restrict__ stTab, double* acc,
               unsigned* ticket, float* __restrict__ out) {
  const int jb = blockIdx.x >> 5;
  const int rb = blockIdx.x & 31;
  const bool emode = (jb >= N_STEPS);
  const int m = emode ? (jb - N_STEPS) : jb / (L_DIM - 1);
  const int l = emode ? (L_DIM - 1) : jb % (L_DIM - 1);
  const bool l0 = (!emode && l == 0);
  const float* X = data + (size_t)(m * L_DIM + l) * (N_PART * 2);

  __shared__ __align__(16) float sTab[TAB_FLOATS];  // 24 KB (EMODE: St-only view)
  __shared__ __align__(16) float Xs[N_PART * 2];    // 4 KB
  __shared__ double sred[8][3];

  const int tid = threadIdx.x;
  if (tid < 256) ((float4*)Xs)[tid] = ((const float4*)X)[tid];
  if (!emode) {
#pragma unroll
    for (int q = 0; q < 3; ++q)
      ((float4*)sTab)[tid + 512 * q] = ((const float4*)tab)[tid + 512 * q];
  } else {
    ((float4*)sTab)[tid] = ((const float4*)stTab)[tid];   // 8 KB packed St
  }
  __syncthreads();

  const int wv = tid >> 6;
  const int ln = tid & 63;
  const int g = ln & 31;               // j-group id / h id (32 lanes per row)
  const int row = rb * 16 + (tid >> 5);
  const float xi0 = Xs[2 * row], xi1 = Xs[2 * row + 1];
  const float invN = 1.0f / N_PART;
  const float invN2 = invN * invN;
  const float rs0 = __builtin_amdgcn_rsqf(1e-20f);
  const float2* Xs2 = (const float2*)Xs;

  float bJd = 0.f, bLap = 0.f, bE = 0.f;       // this wave's 2-row partials

  if (!emode && !l0) {
    // ------- DRIFT: {Sg,Sl} 2-dword gather, no St, no Vi, 3-var reduce ----
    float aGx = 0.f, aGy = 0.f, aLw = 0.f;
#pragma unroll 4
    for (int kk = 0; kk < 16; ++kk) {
      const int j = g + 32 * kk;
      float2 xj = Xs2[j];
      float dx = xi0 - xj.x, dy = xi1 - xj.y;
      float sq = fmaxf(fmaf(dx, dx, dy * dy), 1e-20f);
      float rs = __builtin_amdgcn_rsqf(sq);
      float r = sq * rs;
      int ki = (int)fmaf(r, TSCALE, 0.5f);
      ki = min(ki, NCELL - 1);
      const int b = 3 * ki;
      float Sgv = sTab[b + 1], Slv = sTab[b + 2];
      float tg = Sgv * rs;                      // dPhi / r
      aGx = fmaf(dx, tg, aGx);
      aGy = fmaf(dy, tg, aGy);
      aLw += tg + Slv;                          // d2Phi + dPhi/r (incl diag)
    }
    float gVx, gVy, lapV;
    {
      float w10 = W1[g], w11 = W1[H_DIM + g], w2h = w2[g];
      float arg = TWO_LOG2E * fmaf(xi0, w10, fmaf(xi1, w11, b1[g]));
      float y = __builtin_amdgcn_exp2f(arg);
      float u = __builtin_amdgcn_rcpf(y + 1.0f);
      float t = fmaf(-2.0f, u, 1.0f);
      float dd = fmaf(-u, u, u);
      float g4 = 4.0f * dd * w2h;
      gVx = g4 * w10;
      gVy = g4 * w11;
      lapV = t * dd * (-8.0f * w2h) * fmaf(w10, w10, w11 * w11);
    }
    float gx = fmaf(aGx, invN, gVx);
    float gy = fmaf(aGy, invN, gVy);
    float lw = fmaf(aLw, invN, lapV);
#pragma unroll
    for (int sh = 1; sh < 32; sh <<= 1) {
      gx += __shfl_xor(gx, sh);
      gy += __shfl_xor(gy, sh);
      lw += __shfl_xor(lw, sh);
    }
    lw -= fmaf(sTab[1], rs0, sTab[2]) * invN;   // remove diagonal lap term
    float cJd = fmaf(gx, gx, gy * gy);
    cJd += __shfl_xor(cJd, 32);
    lw += __shfl_xor(lw, 32);
    bJd = cJd; bLap = lw;
  } else if (l0) {
    // ------- L0: full path (identical ops to round-2 unified kernel) ------
    float aSt = 0.f, aGx = 0.f, aGy = 0.f, aLw = 0.f;
#pragma unroll 4
    for (int kk = 0; kk < 16; ++kk) {
      const int j = g + 32 * kk;
      float2 xj = Xs2[j];
      float dx = xi0 - xj.x, dy = xi1 - xj.y;
      float sq = fmaxf(fmaf(dx, dx, dy * dy), 1e-20f);
      float rs = __builtin_amdgcn_rsqf(sq);
      float r = sq * rs;
      int ki = (int)fmaf(r, TSCALE, 0.5f);
      ki = min(ki, NCELL - 1);
      const int b = 3 * ki;
      float Stv = sTab[b], Sgv = sTab[b + 1], Slv = sTab[b + 2];
      float tg = Sgv * rs;
      aSt += Stv;
      aGx = fmaf(dx, tg, aGx);
      aGy = fmaf(dy, tg, aGy);
      aLw += tg + Slv;
    }
    float Vi, gVx, gVy, lapV;
    {
      float w10 = W1[g], w11 = W1[H_DIM + g], w2h = w2[g];
      float arg = TWO_LOG2E * fmaf(xi0, w10, fmaf(xi1, w11, b1[g]));
      float y = __builtin_amdgcn_exp2f(arg);
      float u = __builtin_amdgcn_rcpf(y + 1.0f);
      float t = fmaf(-2.0f, u, 1.0f);
      float dd = fmaf(-u, u, u);
      Vi = t * w2h;
      float g4 = 4.0f * dd * w2h;
      gVx = g4 * w10;
      gVy = g4 * w11;
      lapV = t * dd * (-8.0f * w2h) * fmaf(w10, w10, w11 * w11);
    }
    float eA = fmaf(aSt, invN2, Vi * invN);
    float gx = fmaf(aGx, invN, gVx);
    float gy = fmaf(aGy, invN, gVy);
    float lw = fmaf(aLw, invN, lapV);
#pragma unroll
    for (int sh = 1; sh < 32; sh <<= 1) {
      eA += __shfl_xor(eA, sh);
      gx += __shfl_xor(gx, sh);
      gy += __shfl_xor(gy, sh);
      lw += __shfl_xor(lw, sh);
    }
    eA -= sTab[0] * invN2;
    lw -= fmaf(sTab[1], rs0, sTab[2]) * invN;
    float cJd = fmaf(gx, gx, gy * gy);
    cJd += __shfl_xor(cJd, 32);
    lw += __shfl_xor(lw, 32);
    eA += __shfl_xor(eA, 32);
    bJd = cJd; bLap = lw; bE = eA;
  } else {
    // ------- EMODE: packed St view, 1-dword gather, 1-var reduce ----------
    float aSt = 0.f;
#pragma unroll 4
    for (int kk = 0; kk < 16; ++kk) {
      const int j = g + 32 * kk;
      float2 xj = Xs2[j];
      float dx = xi0 - xj.x, dy = xi1 - xj.y;
      float sq = fmaxf(fmaf(dx, dx, dy * dy), 1e-20f);
      float rs = __builtin_amdgcn_rsqf(sq);
      float r = sq * rs;
      int ki = (int)fmaf(r, TSCALE, 0.5f);
      ki = min(ki, NCELL - 1);
      aSt += sTab[ki];                          // packed St
    }
    float Vi;
    {
      float w10 = W1[g], w11 = W1[H_DIM + g], w2h = w2[g];
      float arg = TWO_LOG2E * fmaf(xi0, w10, fmaf(xi1, w11, b1[g]));
      float y = __builtin_amdgcn_exp2f(arg);
      float u = __builtin_amdgcn_rcpf(y + 1.0f);
      float t = fmaf(-2.0f, u, 1.0f);
      Vi = t * w2h;
    }
    float eA = fmaf(aSt, invN2, Vi * invN);
#pragma unroll
    for (int sh = 1; sh < 32; sh <<= 1) eA += __shfl_xor(eA, sh);
    eA -= sTab[0] * invN2;                      // remove diagonal Phi term
    eA += __shfl_xor(eA, 32);
    bE = eA;
  }

  // ----- per-wave partials -> block partial -> atomic accumulate -----
  if (ln == 0) { sred[wv][0] = bJd; sred[wv][1] = bLap; sred[wv][2] = bE; }
  __syncthreads();
  if (tid == 0) {
    double sJd = 0, sLap = 0, sE = 0;
    for (int w = 0; w < 8; ++w) {
      sJd += sred[w][0]; sLap += sred[w][1]; sE += sred[w][2];
    }
    const double dN = 1.0 / N_PART;
    if (emode) {
      atomicAdd(&acc[2], sE);                   // +E(m, L-1) telescoped
    } else {
      double dt = (double)(tsnap[l + 1] - tsnap[l]);
      atomicAdd(&acc[0], dt * dN * sJd);        // J_diss partial
      atomicAdd(&acc[1], dt * 0.01 * dN * sLap);// J_diff partial
      if (l == 0) atomicAdd(&acc[2], -sE);      // -E(m, 0) telescoped
    }
    // commit my adds at the coherence point BEFORE announcing (plain wait,
    // not a release -> no buffer_wbl2 possible)
    asm volatile("s_waitcnt vmcnt(0)" ::: "memory");
    unsigned old = atomicAdd(ticket, 1u);
    if (old == NBLK - 1) {
      // all 1024 blocks' adds are committed (each waited before bumping;
      // same-address RMWs are totally ordered). Coherent read via
      // returning atomics.
      double s0 = atomicAdd(&acc[0], 0.0);
      double s1 = atomicAdd(&acc[1], 0.0);
      double s2 = atomicAdd(&acc[2], 0.0);
      double r = (s0 + s1 - 2.0 * s2) / (double)N_STEPS;
      out[0] = (float)(r * r);
    }
  }
}

// ---------------------------------------------------------------------------
extern "C" void kernel_launch(void* const* d_in, const int* in_sizes, int n_in,
                              void* d_out, int out_size, void* d_ws, size_t ws_size,
                              hipStream_t stream) {
  (void)in_sizes; (void)n_in; (void)out_size; (void)ws_size;
  const float* data  = (const float*)d_in[0];
  const float* tsnap = (const float*)d_in[1];
  const float* W1    = (const float*)d_in[2];
  const float* b1    = (const float*)d_in[3];
  const float* w2    = (const float*)d_in[4];
  // d_in[5] = b2 (cancels in telescoped dE)
  const float* p1    = (const float*)d_in[6];
  const float* pb1   = (const float*)d_in[7];
  const float* p2    = (const float*)d_in[8];
  // d_in[9] = pb2 (cancels in telescoped dE)
  float* tab = (float*)d_ws;
  float* stTab = (float*)((char*)d_ws + ST_OFF);
  double* acc = (double*)((char*)d_ws + ACC_OFF);
  unsigned* ticket = (unsigned*)((char*)d_ws + TICKET_OFF);
  float* out = (float*)d_out;

  hipLaunchKernelGGL(tfl_tabgen, dim3(NCELL / 256), dim3(256), 0, stream,
                     p1, pb1, p2, tab, stTab, acc, ticket);
  hipLaunchKernelGGL(tfl_main9, dim3(NBLK), dim3(512), 0, stream,
                     data, tsnap, W1, b1, w2, tab, stTab, acc, ticket, out);
}

// Round 6
// 20.953 us; speedup vs baseline: 2.4769x; 2.4769x over previous
//
#include <hip/hip_runtime.h>

#define N_PART 512
#define H_DIM 32
#define M_DIM 4
#define L_DIM 8
#define N_STEPS (M_DIM * (L_DIM - 1))   // 28
#define N_JOBS (N_STEPS + M_DIM)        // 32
#define BLK_PER_JOB 16                  // 16 blocks x 32 rows = 512 rows
#define NBLK (N_JOBS * BLK_PER_JOB)     // 512 blocks, 1024 threads each
#define NCELL 2048
#define RMAX 10.0f
#define TSCALE ((float)NCELL / RMAX)    // 204.8
#define TWO_LOG2E 2.8853900817779268f

// ws layout (three PACKED 4B-stride planes -> per-plane gathers hit bank
// ki%32, full 32-bank spread; round-3 lesson: interleaved 8B-stride pairs
// alias to even banks only):
//  [0,  8KB)   stTab float[2048]
//  [8K, 16KB)  sgTab float[2048]
//  [16K,24KB)  slTab float[2048]
//  [24K,36KB)  partials double[512][3]
#define PLANE_FLOATS NCELL
#define ST_OFF 0
#define SG_OFF (NCELL * 4)
#define SL_OFF (NCELL * 8)
#define PART_OFF (NCELL * 12)

// ---------------------------------------------------------------------------
// Build the r-tables: cell c holds St (Phi), Sg (dPhi), Sl (d2Phi) at
// r = c/TSCALE, as three packed planes.
__global__ __launch_bounds__(256)
void tfl_tabgen(const float* __restrict__ p1, const float* __restrict__ pb1,
                const float* __restrict__ p2, float* __restrict__ stTab,
                float* __restrict__ sgTab, float* __restrict__ slTab) {
  const int c = blockIdx.x * 256 + threadIdx.x;
  if (c >= NCELL) return;
  const float r = (float)c * (RMAX / (float)NCELL);
  float St = 0.f, Sg = 0.f, Sl = 0.f;
  for (int h = 0; h < H_DIM; ++h) {
    float p1h = p1[h], P2h = p2[h];
    float arg = TWO_LOG2E * fmaf(r, p1h, pb1[h]);
    float y = __builtin_amdgcn_exp2f(arg);
    float u = __builtin_amdgcn_rcpf(y + 1.0f);
    float t = fmaf(-2.0f, u, 1.0f);            // tanh
    float dd = fmaf(-u, u, u);                 // sech^2 / 4
    St = fmaf(t, P2h, St);
    Sg = fmaf(dd, 4.0f * p1h * P2h, Sg);       // dPhi
    Sl = fmaf(t * dd, -8.0f * p1h * p1h * P2h, Sl);  // d2Phi
  }
  stTab[c] = St;
  sgTab[c] = Sg;
  slTab[c] = Sl;
}

// ---------------------------------------------------------------------------
// Main: 512 blocks = 32 jobs x 16 block-halves, 1024 threads (2 blocks/CU,
// 32 waves/CU). Each block owns 32 rows: 32 threads/row, 16 j's per thread.
// Mode-specialized staging & reads on packed planes (E telescoped):
//   DRIFT (l=1..6): stage sg+sl (16 KB); 2 plane gathers; 3-var reduce.
//   L0    (l==0)  : stage all three (24 KB); 3 gathers; 4-var reduce.
//   EMODE (l==7)  : stage st only (8 KB); 1 gather; 1-var reduce.
// No cross-block sync (rounds 1/3/5: fences emit L2 maintenance, and f64
// atomicAdd is a contended CAS loop -> both lose vs a separate finalize).
__global__ __launch_bounds__(1024)
void tfl_main10(const float* __restrict__ data, const float* __restrict__ tsnap,
                const float* __restrict__ W1, const float* __restrict__ b1,
                const float* __restrict__ w2, const float* __restrict__ tabAll,
                double* __restrict__ partials) {
  const int jb = blockIdx.x >> 4;
  const int rb = blockIdx.x & 15;
  const bool emode = (jb >= N_STEPS);
  const int m = emode ? (jb - N_STEPS) : jb / (L_DIM - 1);
  const int l = emode ? (L_DIM - 1) : jb % (L_DIM - 1);
  const bool l0 = (!emode && l == 0);
  const float* X = data + (size_t)(m * L_DIM + l) * (N_PART * 2);

  __shared__ __align__(16) float sPl[NCELL * 3];   // st | sg | sl planes, 24 KB
  __shared__ __align__(16) float Xs[N_PART * 2];   // 4 KB
  __shared__ double sred[16][3];

  float* const sSt = sPl;
  float* const sSg = sPl + NCELL;
  float* const sSl = sPl + 2 * NCELL;

  const int tid = threadIdx.x;
  if (tid < 256) ((float4*)Xs)[tid] = ((const float4*)X)[tid];
  if (!emode && !l0) {
    // sg+sl planes: global float4 idx 512..1535 -> same LDS float4 slots
    ((float4*)sPl)[512 + tid] = ((const float4*)tabAll)[512 + tid];
  } else if (l0) {
    ((float4*)sPl)[tid] = ((const float4*)tabAll)[tid];
    if (tid < 512)
      ((float4*)sPl)[1024 + tid] = ((const float4*)tabAll)[1024 + tid];
  } else {
    if (tid < 512) ((float4*)sPl)[tid] = ((const float4*)tabAll)[tid];
  }
  __syncthreads();

  const int wv = tid >> 6;             // 0..15
  const int ln = tid & 63;
  const int g = ln & 31;               // j-group id / h id (32 lanes per row)
  const int row = rb * 32 + (tid >> 5);
  const float xi0 = Xs[2 * row], xi1 = Xs[2 * row + 1];
  const float invN = 1.0f / N_PART;
  const float invN2 = invN * invN;
  const float rs0 = __builtin_amdgcn_rsqf(1e-20f);
  const float2* Xs2 = (const float2*)Xs;

  float bJd = 0.f, bLap = 0.f, bE = 0.f;       // this wave's 2-row partials

  if (!emode && !l0) {
    // ------- DRIFT: sg+sl plane gathers, no St, no Vi, 3-var reduce -------
    float aGx = 0.f, aGy = 0.f, aLw = 0.f;
#pragma unroll 4
    for (int kk = 0; kk < 16; ++kk) {
      const int j = g + 32 * kk;
      float2 xj = Xs2[j];
      float dx = xi0 - xj.x, dy = xi1 - xj.y;
      float sq = fmaxf(fmaf(dx, dx, dy * dy), 1e-20f);
      float rs = __builtin_amdgcn_rsqf(sq);
      float r = sq * rs;
      int ki = (int)fmaf(r, TSCALE, 0.5f);
      ki = min(ki, NCELL - 1);
      float Sgv = sSg[ki], Slv = sSl[ki];
      float tg = Sgv * rs;                      // dPhi / r
      aGx = fmaf(dx, tg, aGx);
      aGy = fmaf(dy, tg, aGy);
      aLw += tg + Slv;                          // d2Phi + dPhi/r (incl diag)
    }
    float gVx, gVy, lapV;
    {
      float w10 = W1[g], w11 = W1[H_DIM + g], w2h = w2[g];
      float arg = TWO_LOG2E * fmaf(xi0, w10, fmaf(xi1, w11, b1[g]));
      float y = __builtin_amdgcn_exp2f(arg);
      float u = __builtin_amdgcn_rcpf(y + 1.0f);
      float t = fmaf(-2.0f, u, 1.0f);
      float dd = fmaf(-u, u, u);
      float g4 = 4.0f * dd * w2h;
      gVx = g4 * w10;
      gVy = g4 * w11;
      lapV = t * dd * (-8.0f * w2h) * fmaf(w10, w10, w11 * w11);
    }
    float gx = fmaf(aGx, invN, gVx);
    float gy = fmaf(aGy, invN, gVy);
    float lw = fmaf(aLw, invN, lapV);
#pragma unroll
    for (int sh = 1; sh < 32; sh <<= 1) {
      gx += __shfl_xor(gx, sh);
      gy += __shfl_xor(gy, sh);
      lw += __shfl_xor(lw, sh);
    }
    lw -= fmaf(sSg[0], rs0, sSl[0]) * invN;     // remove diagonal lap term
    float cJd = fmaf(gx, gx, gy * gy);
    cJd += __shfl_xor(cJd, 32);
    lw += __shfl_xor(lw, 32);
    bJd = cJd; bLap = lw;
  } else if (l0) {
    // ------- L0: full path (drift + lap + E), 4-var reduce ----------------
    float aSt = 0.f, aGx = 0.f, aGy = 0.f, aLw = 0.f;
#pragma unroll 4
    for (int kk = 0; kk < 16; ++kk) {
      const int j = g + 32 * kk;
      float2 xj = Xs2[j];
      float dx = xi0 - xj.x, dy = xi1 - xj.y;
      float sq = fmaxf(fmaf(dx, dx, dy * dy), 1e-20f);
      float rs = __builtin_amdgcn_rsqf(sq);
      float r = sq * rs;
      int ki = (int)fmaf(r, TSCALE, 0.5f);
      ki = min(ki, NCELL - 1);
      float Stv = sSt[ki], Sgv = sSg[ki], Slv = sSl[ki];
      float tg = Sgv * rs;
      aSt += Stv;
      aGx = fmaf(dx, tg, aGx);
      aGy = fmaf(dy, tg, aGy);
      aLw += tg + Slv;
    }
    float Vi, gVx, gVy, lapV;
    {
      float w10 = W1[g], w11 = W1[H_DIM + g], w2h = w2[g];
      float arg = TWO_LOG2E * fmaf(xi0, w10, fmaf(xi1, w11, b1[g]));
      float y = __builtin_amdgcn_exp2f(arg);
      float u = __builtin_amdgcn_rcpf(y + 1.0f);
      float t = fmaf(-2.0f, u, 1.0f);
      float dd = fmaf(-u, u, u);
      Vi = t * w2h;
      float g4 = 4.0f * dd * w2h;
      gVx = g4 * w10;
      gVy = g4 * w11;
      lapV = t * dd * (-8.0f * w2h) * fmaf(w10, w10, w11 * w11);
    }
    float eA = fmaf(aSt, invN2, Vi * invN);
    float gx = fmaf(aGx, invN, gVx);
    float gy = fmaf(aGy, invN, gVy);
    float lw = fmaf(aLw, invN, lapV);
#pragma unroll
    for (int sh = 1; sh < 32; sh <<= 1) {
      eA += __shfl_xor(eA, sh);
      gx += __shfl_xor(gx, sh);
      gy += __shfl_xor(gy, sh);
      lw += __shfl_xor(lw, sh);
    }
    eA -= sSt[0] * invN2;
    lw -= fmaf(sSg[0], rs0, sSl[0]) * invN;
    float cJd = fmaf(gx, gx, gy * gy);
    cJd += __shfl_xor(cJd, 32);
    lw += __shfl_xor(lw, 32);
    eA += __shfl_xor(eA, 32);
    bJd = cJd; bLap = lw; bE = eA;
  } else {
    // ------- EMODE: st plane only, 1 gather, 1-var reduce -----------------
    float aSt = 0.f;
#pragma unroll 4
    for (int kk = 0; kk < 16; ++kk) {
      const int j = g + 32 * kk;
      float2 xj = Xs2[j];
      float dx = xi0 - xj.x, dy = xi1 - xj.y;
      float sq = fmaxf(fmaf(dx, dx, dy * dy), 1e-20f);
      float rs = __builtin_amdgcn_rsqf(sq);
      float r = sq * rs;
      int ki = (int)fmaf(r, TSCALE, 0.5f);
      ki = min(ki, NCELL - 1);
      aSt += sSt[ki];
    }
    float Vi;
    {
      float w10 = W1[g], w11 = W1[H_DIM + g], w2h = w2[g];
      float arg = TWO_LOG2E * fmaf(xi0, w10, fmaf(xi1, w11, b1[g]));
      float y = __builtin_amdgcn_exp2f(arg);
      float u = __builtin_amdgcn_rcpf(y + 1.0f);
      float t = fmaf(-2.0f, u, 1.0f);
      Vi = t * w2h;
    }
    float eA = fmaf(aSt, invN2, Vi * invN);
#pragma unroll
    for (int sh = 1; sh < 32; sh <<= 1) eA += __shfl_xor(eA, sh);
    eA -= sSt[0] * invN2;                       // remove diagonal Phi term
    eA += __shfl_xor(eA, 32);
    bE = eA;
  }

  // ----- per-wave partials -> block partial -> global store -----
  if (ln == 0) { sred[wv][0] = bJd; sred[wv][1] = bLap; sred[wv][2] = bE; }
  __syncthreads();
  if (tid == 0) {
    double sJd = 0, sLap = 0, sE = 0;
    for (int w = 0; w < 16; ++w) {
      sJd += sred[w][0]; sLap += sred[w][1]; sE += sred[w][2];
    }
    const double dN = 1.0 / N_PART;
    double j0 = 0.0, j1 = 0.0, j2 = 0.0;
    if (emode) {
      j2 = sE;                                  // +E(m, L-1) telescoped
    } else {
      double dt = (double)(tsnap[l + 1] - tsnap[l]);
      j0 = dt * dN * sJd;                       // J_diss partial
      j1 = dt * 0.01 * dN * sLap;               // J_diff partial
      if (l == 0) j2 = -sE;                     // -E(m, 0) telescoped
    }
    partials[(size_t)blockIdx.x * 3 + 0] = j0;
    partials[(size_t)blockIdx.x * 3 + 1] = j1;
    partials[(size_t)blockIdx.x * 3 + 2] = j2;
  }
}

// ---------------------------------------------------------------------------
// 1 block, 512 threads: one partial triplet each, 6-step 64-lane shuffle
// reduce + 8-wave LDS combine (one barrier).
__global__ __launch_bounds__(512)
void tfl_finalize(const double* __restrict__ partials, float* __restrict__ out) {
  __shared__ double sred[8][3];
  const int tid = threadIdx.x;
  const int wv = tid >> 6;
  const int ln = tid & 63;
  const double* pa = partials + (size_t)tid * 3;
  double t0 = pa[0], t1 = pa[1], t2 = pa[2];
#pragma unroll
  for (int sh = 1; sh < 64; sh <<= 1) {
    t0 += __shfl_xor(t0, sh);
    t1 += __shfl_xor(t1, sh);
    t2 += __shfl_xor(t2, sh);
  }
  if (ln == 0) { sred[wv][0] = t0; sred[wv][1] = t1; sred[wv][2] = t2; }
  __syncthreads();
  if (tid == 0) {
    double s0 = 0, s1 = 0, s2 = 0;
    for (int w = 0; w < 8; ++w) {
      s0 += sred[w][0]; s1 += sred[w][1]; s2 += sred[w][2];
    }
    double r = (s0 + s1 - 2.0 * s2) / (double)N_STEPS;
    out[0] = (float)(r * r);
  }
}

// ---------------------------------------------------------------------------
extern "C" void kernel_launch(void* const* d_in, const int* in_sizes, int n_in,
                              void* d_out, int out_size, void* d_ws, size_t ws_size,
                              hipStream_t stream) {
  (void)in_sizes; (void)n_in; (void)out_size; (void)ws_size;
  const float* data  = (const float*)d_in[0];
  const float* tsnap = (const float*)d_in[1];
  const float* W1    = (const float*)d_in[2];
  const float* b1    = (const float*)d_in[3];
  const float* w2    = (const float*)d_in[4];
  // d_in[5] = b2 (cancels in telescoped dE)
  const float* p1    = (const float*)d_in[6];
  const float* pb1   = (const float*)d_in[7];
  const float* p2    = (const float*)d_in[8];
  // d_in[9] = pb2 (cancels in telescoped dE)
  float* tabAll = (float*)d_ws;                  // st | sg | sl planes
  float* stTab = (float*)((char*)d_ws + ST_OFF);
  float* sgTab = (float*)((char*)d_ws + SG_OFF);
  float* slTab = (float*)((char*)d_ws + SL_OFF);
  double* partials = (double*)((char*)d_ws + PART_OFF);
  float* out = (float*)d_out;

  hipLaunchKernelGGL(tfl_tabgen, dim3(NCELL / 256), dim3(256), 0, stream,
                     p1, pb1, p2, stTab, sgTab, slTab);
  hipLaunchKernelGGL(tfl_main10, dim3(NBLK), dim3(1024), 0, stream,
                     data, tsnap, W1, b1, w2, tabAll, partials);
  hipLaunchKernelGGL(tfl_finalize, dim3(1), dim3(512), 0, stream, partials, out);
}

// Round 8
// 19.575 us; speedup vs baseline: 2.6512x; 1.0704x over previous
//
#include <hip/hip_runtime.h>

#define N_PART 512
#define H_DIM 32
#define M_DIM 4
#define L_DIM 8
#define N_STEPS (M_DIM * (L_DIM - 1))   // 28
#define N_JOBS (N_STEPS + M_DIM)        // 32
#define NBLK (N_JOBS * 32)              // 1024 (32 rowgroups of 16 rows)
#define NCELL 2048
#define RMAX 10.0f
#define TSCALE ((float)NCELL / RMAX)    // 204.8
#define TWO_LOG2E 2.8853900817779268f

// ws layout:
//  [0, 24KB)    tab    float3[2048] {St,Sg,Sl}  (12B stride: full bank spread)
//  [24KB, 32KB) stTab  float[2048]  (packed St for EMODE's 8KB staging)
//  [32KB, 56KB) partials double[1024][3]
#define TAB_FLOATS (NCELL * 3)
#define TAB_BYTES (TAB_FLOATS * 4)
#define ST_OFF TAB_BYTES
#define ST_BYTES (NCELL * 4)
#define PART_OFF (TAB_BYTES + ST_BYTES)

// ---------------------------------------------------------------------------
// DPP-based 32-lane sum reduction: keeps the reduce OFF the LDS pipe
// (__shfl_xor lowers to ds_swizzle/ds_permute -> competes with the table
// gathers; DPP row ops issue on the VALU). Template parameters so the
// builtin sees integer constant expressions (round-7 compile fix).
// After red32(), every lane of DPP-rows 1,3 (lanes 16-31 / 48-63) holds the
// full 32-lane sum of its half-wave.
template <int CTRL, int RMASK>
__device__ __forceinline__ float dppadd(float v) {
  int p = __builtin_amdgcn_update_dpp(0, __float_as_int(v), CTRL, RMASK, 0xF,
                                      false);   // masked rows: old=0 -> +0
  return v + __int_as_float(p);
}
__device__ __forceinline__ float red32(float v) {
  v = dppadd<0xB1, 0xF>(v);    // quad_perm [1,0,3,2]  : xor 1
  v = dppadd<0x4E, 0xF>(v);    // quad_perm [2,3,0,1]  : xor 2
  v = dppadd<0x141, 0xF>(v);   // row_half_mirror      : pair 4s within 8
  v = dppadd<0x140, 0xF>(v);   // row_mirror           : pair 8s within 16
  v = dppadd<0x142, 0xA>(v);   // row_bcast15 -> rows 1,3 get 32-sums
  return v;
}

// ---------------------------------------------------------------------------
// Build the r-tables: cell c holds {St, Sg, Sl} at r = c/TSCALE, plus a
// packed St-only copy for EMODE blocks' lighter staging.
__global__ __launch_bounds__(256)
void tfl_tabgen(const float* __restrict__ p1, const float* __restrict__ pb1,
                const float* __restrict__ p2, float* __restrict__ tab,
                float* __restrict__ stTab) {
  const int c = blockIdx.x * 256 + threadIdx.x;
  if (c >= NCELL) return;
  const float r = (float)c * (RMAX / (float)NCELL);
  float St = 0.f, Sg = 0.f, Sl = 0.f;
  for (int h = 0; h < H_DIM; ++h) {
    float p1h = p1[h], P2h = p2[h];
    float arg = TWO_LOG2E * fmaf(r, p1h, pb1[h]);
    float y = __builtin_amdgcn_exp2f(arg);
    float u = __builtin_amdgcn_rcpf(y + 1.0f);
    float t = fmaf(-2.0f, u, 1.0f);            // tanh
    float dd = fmaf(-u, u, u);                 // sech^2 / 4
    St = fmaf(t, P2h, St);
    Sg = fmaf(dd, 4.0f * p1h * P2h, Sg);       // dPhi
    Sl = fmaf(t * dd, -8.0f * p1h * p1h * P2h, Sl);  // d2Phi
  }
  tab[3 * c + 0] = St;
  tab[3 * c + 1] = Sg;
  tab[3 * c + 2] = Sl;
  stTab[c] = St;
}

// ---------------------------------------------------------------------------
// Main: 1024 blocks = 32 jobs x 32 rowgroups(16 rows). 512 threads:
// 32 threads per row, each thread owns 16 j's. Single float3 table (12B
// stride -> gcd(3,32)=1 -> random gathers spread over all 32 banks).
// Mode-specialized READS (E telescoped): DRIFT / L0 / EMODE as round 4.
// NEW vs round 4: all 32-lane reductions via DPP (VALU pipe) instead of
// __shfl_xor (LDS pipe) -> DRIFT reduce ds-ops 17 -> 3 per wave. Writer
// lane is ln==16 (where bcast15 leaves the 32-sums).
// No cross-block sync (rounds 1/3/5: L2 maintenance + f64 CAS contention).
__global__ __launch_bounds__(512)
void tfl_main11(const float* __restrict__ data, const float* __restrict__ tsnap,
                const float* __restrict__ W1, const float* __restrict__ b1,
                const float* __restrict__ w2, const float* __restrict__ tab,
                const float* __restrict__ stTab, double* __restrict__ partials) {
  const int jb = blockIdx.x >> 5;
  const int rb = blockIdx.x & 31;
  const bool emode = (jb >= N_STEPS);
  const int m = emode ? (jb - N_STEPS) : jb / (L_DIM - 1);
  const int l = emode ? (L_DIM - 1) : jb % (L_DIM - 1);
  const bool l0 = (!emode && l == 0);
  const float* X = data + (size_t)(m * L_DIM + l) * (N_PART * 2);

  __shared__ __align__(16) float sTab[TAB_FLOATS];  // 24 KB (EMODE: St-only view)
  __shared__ __align__(16) float Xs[N_PART * 2];    // 4 KB
  __shared__ double sred[8][3];

  const int tid = threadIdx.x;
  if (tid < 256) ((float4*)Xs)[tid] = ((const float4*)X)[tid];
  if (!emode) {
#pragma unroll
    for (int q = 0; q < 3; ++q)
      ((float4*)sTab)[tid + 512 * q] = ((const float4*)tab)[tid + 512 * q];
  } else {
    ((float4*)sTab)[tid] = ((const float4*)stTab)[tid];   // 8 KB packed St
  }
  __syncthreads();

  const int wv = tid >> 6;
  const int ln = tid & 63;
  const int g = ln & 31;               // j-group id / h id (32 lanes per row)
  const int row = rb * 16 + (tid >> 5);
  const float xi0 = Xs[2 * row], xi1 = Xs[2 * row + 1];
  const float invN = 1.0f / N_PART;
  const float invN2 = invN * invN;
  const float rs0 = __builtin_amdgcn_rsqf(1e-20f);
  const float2* Xs2 = (const float2*)Xs;

  float bJd = 0.f, bLap = 0.f, bE = 0.f;       // this wave's 2-row partials

  if (!emode && !l0) {
    // ------- DRIFT: {Sg,Sl} 2-dword gather, no St, no Vi, 3-var reduce ----
    float aGx = 0.f, aGy = 0.f, aLw = 0.f;
#pragma unroll 4
    for (int kk = 0; kk < 16; ++kk) {
      const int j = g + 32 * kk;
      float2 xj = Xs2[j];
      float dx = xi0 - xj.x, dy = xi1 - xj.y;
      float sq = fmaxf(fmaf(dx, dx, dy * dy), 1e-20f);
      float rs = __builtin_amdgcn_rsqf(sq);
      float r = sq * rs;
      int ki = (int)fmaf(r, TSCALE, 0.5f);
      ki = min(ki, NCELL - 1);
      const int b = 3 * ki;
      float Sgv = sTab[b + 1], Slv = sTab[b + 2];   // merges to ds_read2_b32
      float tg = Sgv * rs;                      // dPhi / r
      aGx = fmaf(dx, tg, aGx);
      aGy = fmaf(dy, tg, aGy);
      aLw += tg + Slv;                          // d2Phi + dPhi/r (incl diag)
    }
    float gVx, gVy, lapV;
    {
      float w10 = W1[g], w11 = W1[H_DIM + g], w2h = w2[g];
      float arg = TWO_LOG2E * fmaf(xi0, w10, fmaf(xi1, w11, b1[g]));
      float y = __builtin_amdgcn_exp2f(arg);
      float u = __builtin_amdgcn_rcpf(y + 1.0f);
      float t = fmaf(-2.0f, u, 1.0f);
      float dd = fmaf(-u, u, u);
      float g4 = 4.0f * dd * w2h;
      gVx = g4 * w10;
      gVy = g4 * w11;
      lapV = t * dd * (-8.0f * w2h) * fmaf(w10, w10, w11 * w11);
    }
    float gx = red32(fmaf(aGx, invN, gVx));
    float gy = red32(fmaf(aGy, invN, gVy));
    float lw = red32(fmaf(aLw, invN, lapV));
    lw -= fmaf(sTab[1], rs0, sTab[2]) * invN;   // remove diagonal lap term
    float cJd = fmaf(gx, gx, gy * gy);
    cJd += __shfl_xor(cJd, 32);
    lw += __shfl_xor(lw, 32);
    bJd = cJd; bLap = lw;
  } else if (l0) {
    // ------- L0: full path (drift + lap + E), 4-var reduce ----------------
    float aSt = 0.f, aGx = 0.f, aGy = 0.f, aLw = 0.f;
#pragma unroll 4
    for (int kk = 0; kk < 16; ++kk) {
      const int j = g + 32 * kk;
      float2 xj = Xs2[j];
      float dx = xi0 - xj.x, dy = xi1 - xj.y;
      float sq = fmaxf(fmaf(dx, dx, dy * dy), 1e-20f);
      float rs = __builtin_amdgcn_rsqf(sq);
      float r = sq * rs;
      int ki = (int)fmaf(r, TSCALE, 0.5f);
      ki = min(ki, NCELL - 1);
      const int b = 3 * ki;
      float Stv = sTab[b], Sgv = sTab[b + 1], Slv = sTab[b + 2];
      float tg = Sgv * rs;
      aSt += Stv;
      aGx = fmaf(dx, tg, aGx);
      aGy = fmaf(dy, tg, aGy);
      aLw += tg + Slv;
    }
    float Vi, gVx, gVy, lapV;
    {
      float w10 = W1[g], w11 = W1[H_DIM + g], w2h = w2[g];
      float arg = TWO_LOG2E * fmaf(xi0, w10, fmaf(xi1, w11, b1[g]));
      float y = __builtin_amdgcn_exp2f(arg);
      float u = __builtin_amdgcn_rcpf(y + 1.0f);
      float t = fmaf(-2.0f, u, 1.0f);
      float dd = fmaf(-u, u, u);
      Vi = t * w2h;
      float g4 = 4.0f * dd * w2h;
      gVx = g4 * w10;
      gVy = g4 * w11;
      lapV = t * dd * (-8.0f * w2h) * fmaf(w10, w10, w11 * w11);
    }
    float eA = red32(fmaf(aSt, invN2, Vi * invN));
    float gx = red32(fmaf(aGx, invN, gVx));
    float gy = red32(fmaf(aGy, invN, gVy));
    float lw = red32(fmaf(aLw, invN, lapV));
    eA -= sTab[0] * invN2;
    lw -= fmaf(sTab[1], rs0, sTab[2]) * invN;
    float cJd = fmaf(gx, gx, gy * gy);
    cJd += __shfl_xor(cJd, 32);
    lw += __shfl_xor(lw, 32);
    eA += __shfl_xor(eA, 32);
    bJd = cJd; bLap = lw; bE = eA;
  } else {
    // ------- EMODE: packed St view, 1-dword gather, 1-var reduce ----------
    float aSt = 0.f;
#pragma unroll 4
    for (int kk = 0; kk < 16; ++kk) {
      const int j = g + 32 * kk;
      float2 xj = Xs2[j];
      float dx = xi0 - xj.x, dy = xi1 - xj.y;
      float sq = fmaxf(fmaf(dx, dx, dy * dy), 1e-20f);
      float rs = __builtin_amdgcn_rsqf(sq);
      float r = sq * rs;
      int ki = (int)fmaf(r, TSCALE, 0.5f);
      ki = min(ki, NCELL - 1);
      aSt += sTab[ki];                          // packed St
    }
    float Vi;
    {
      float w10 = W1[g], w11 = W1[H_DIM + g], w2h = w2[g];
      float arg = TWO_LOG2E * fmaf(xi0, w10, fmaf(xi1, w11, b1[g]));
      float y = __builtin_amdgcn_exp2f(arg);
      float u = __builtin_amdgcn_rcpf(y + 1.0f);
      float t = fmaf(-2.0f, u, 1.0f);
      Vi = t * w2h;
    }
    float eA = red32(fmaf(aSt, invN2, Vi * invN));
    eA -= sTab[0] * invN2;                      // remove diagonal Phi term
    eA += __shfl_xor(eA, 32);
    bE = eA;
  }

  // ----- per-wave partials -> block partial -> global store -----
  // (32-sums live in DPP-rows 1,3; after the xor-32 combine, lane 16 holds
  //  the wave total)
  if (ln == 16) { sred[wv][0] = bJd; sred[wv][1] = bLap; sred[wv][2] = bE; }
  __syncthreads();
  if (tid == 0) {
    double sJd = 0, sLap = 0, sE = 0;
    for (int w = 0; w < 8; ++w) {
      sJd += sred[w][0]; sLap += sred[w][1]; sE += sred[w][2];
    }
    const double dN = 1.0 / N_PART;
    double j0 = 0.0, j1 = 0.0, j2 = 0.0;
    if (emode) {
      j2 = sE;                                  // +E(m, L-1) telescoped
    } else {
      double dt = (double)(tsnap[l + 1] - tsnap[l]);
      j0 = dt * dN * sJd;                       // J_diss partial
      j1 = dt * 0.01 * dN * sLap;               // J_diff partial
      if (l == 0) j2 = -sE;                     // -E(m, 0) telescoped
    }
    partials[(size_t)blockIdx.x * 3 + 0] = j0;
    partials[(size_t)blockIdx.x * 3 + 1] = j1;
    partials[(size_t)blockIdx.x * 3 + 2] = j2;
  }
}

// ---------------------------------------------------------------------------
// 1 block, 512 threads: each thread sums 2 partial triplets, then a 6-step
// 64-lane shuffle reduce + 8-wave LDS combine (one barrier).
__global__ __launch_bounds__(512)
void tfl_finalize(const double* __restrict__ partials, float* __restrict__ out) {
  __shared__ double sred[8][3];
  const int tid = threadIdx.x;
  const int wv = tid >> 6;
  const int ln = tid & 63;
  const double* pa = partials + (size_t)tid * 3;
  const double* pb = partials + (size_t)(tid + 512) * 3;
  double t0 = pa[0] + pb[0];
  double t1 = pa[1] + pb[1];
  double t2 = pa[2] + pb[2];
#pragma unroll
  for (int sh = 1; sh < 64; sh <<= 1) {
    t0 += __shfl_xor(t0, sh);
    t1 += __shfl_xor(t1, sh);
    t2 += __shfl_xor(t2, sh);
  }
  if (ln == 0) { sred[wv][0] = t0; sred[wv][1] = t1; sred[wv][2] = t2; }
  __syncthreads();
  if (tid == 0) {
    double s0 = 0, s1 = 0, s2 = 0;
    for (int w = 0; w < 8; ++w) {
      s0 += sred[w][0]; s1 += sred[w][1]; s2 += sred[w][2];
    }
    double r = (s0 + s1 - 2.0 * s2) / (double)N_STEPS;
    out[0] = (float)(r * r);
  }
}

// ---------------------------------------------------------------------------
extern "C" void kernel_launch(void* const* d_in, const int* in_sizes, int n_in,
                              void* d_out, int out_size, void* d_ws, size_t ws_size,
                              hipStream_t stream) {
  (void)in_sizes; (void)n_in; (void)out_size; (void)ws_size;
  const float* data  = (const float*)d_in[0];
  const float* tsnap = (const float*)d_in[1];
  const float* W1    = (const float*)d_in[2];
  const float* b1    = (const float*)d_in[3];
  const float* w2    = (const float*)d_in[4];
  // d_in[5] = b2 (cancels in telescoped dE)
  const float* p1    = (const float*)d_in[6];
  const float* pb1   = (const float*)d_in[7];
  const float* p2    = (const float*)d_in[8];
  // d_in[9] = pb2 (cancels in telescoped dE)
  float* tab = (float*)d_ws;
  float* stTab = (float*)((char*)d_ws + ST_OFF);
  double* partials = (double*)((char*)d_ws + PART_OFF);
  float* out = (float*)d_out;

  hipLaunchKernelGGL(tfl_tabgen, dim3(NCELL / 256), dim3(256), 0, stream,
                     p1, pb1, p2, tab, stTab);
  hipLaunchKernelGGL(tfl_main11, dim3(NBLK), dim3(512), 0, stream,
                     data, tsnap, W1, b1, w2, tab, stTab, partials);
  hipLaunchKernelGGL(tfl_finalize, dim3(1), dim3(512), 0, stream, partials, out);
}

// Round 9
// 18.592 us; speedup vs baseline: 2.7914x; 1.0529x over previous
//
#include <hip/hip_runtime.h>
#include <hip/hip_fp16.h>

#define N_PART 512
#define H_DIM 32
#define M_DIM 4
#define L_DIM 8
#define N_STEPS (M_DIM * (L_DIM - 1))   // 28
#define N_JOBS (N_STEPS + M_DIM)        // 32
#define NBLK (N_JOBS * 32)              // 1024 (32 rowgroups of 16 rows)
#define NCELL 2048
#define RMAX 10.0f
#define TSCALE ((float)NCELL / RMAX)    // 204.8
#define TWO_LOG2E 2.8853900817779268f

// ws layout (two 4B-stride planes -> full 32-bank spread on random gathers;
// round-3 lesson: 8B-stride pairs alias to even banks):
//  [0, 8KB)     stTab  float[2048]     St (f32 — feeds telescoped E)
//  [8K, 16KB)   gsTab  uint[2048]      packed {Sg,Sl} as 2xf16
//  [16K, 40KB)  partials double[1024][3]
#define ST_OFF 0
#define GS_OFF (NCELL * 4)
#define PART_OFF (NCELL * 8)

// ---------------------------------------------------------------------------
// DPP-based 32-lane sum reduction (round-8 win: reduce on VALU pipe, not the
// contended LDS pipe). After red32(), every lane of DPP-rows 1,3 (lanes
// 16-31 / 48-63) holds the full 32-lane sum of its half-wave.
template <int CTRL, int RMASK>
__device__ __forceinline__ float dppadd(float v) {
  int p = __builtin_amdgcn_update_dpp(0, __float_as_int(v), CTRL, RMASK, 0xF,
                                      false);   // masked rows: old=0 -> +0
  return v + __int_as_float(p);
}
__device__ __forceinline__ float red32(float v) {
  v = dppadd<0xB1, 0xF>(v);    // quad_perm [1,0,3,2]  : xor 1
  v = dppadd<0x4E, 0xF>(v);    // quad_perm [2,3,0,1]  : xor 2
  v = dppadd<0x141, 0xF>(v);   // row_half_mirror      : pair 4s within 8
  v = dppadd<0x140, 0xF>(v);   // row_mirror           : pair 8s within 16
  v = dppadd<0x142, 0xA>(v);   // row_bcast15 -> rows 1,3 get 32-sums
  return v;
}

__device__ __forceinline__ float2 unpack_gs(unsigned w) {
  return make_float2(
      __half2float(__ushort_as_half((unsigned short)(w & 0xFFFFu))),
      __half2float(__ushort_as_half((unsigned short)(w >> 16))));
}

// ---------------------------------------------------------------------------
// Build the r-tables: cell c holds St (f32) and packed {Sg,Sl} (2xf16) at
// r = c/TSCALE. f16 rel err ~5e-4 << the ~2.5e-3 nearest-cell quantization
// already present, so the packing is below the established noise floor.
__global__ __launch_bounds__(256)
void tfl_tabgen(const float* __restrict__ p1, const float* __restrict__ pb1,
                const float* __restrict__ p2, float* __restrict__ stTab,
                unsigned* __restrict__ gsTab) {
  const int c = blockIdx.x * 256 + threadIdx.x;
  if (c >= NCELL) return;
  const float r = (float)c * (RMAX / (float)NCELL);
  float St = 0.f, Sg = 0.f, Sl = 0.f;
  for (int h = 0; h < H_DIM; ++h) {
    float p1h = p1[h], P2h = p2[h];
    float arg = TWO_LOG2E * fmaf(r, p1h, pb1[h]);
    float y = __builtin_amdgcn_exp2f(arg);
    float u = __builtin_amdgcn_rcpf(y + 1.0f);
    float t = fmaf(-2.0f, u, 1.0f);            // tanh
    float dd = fmaf(-u, u, u);                 // sech^2 / 4
    St = fmaf(t, P2h, St);
    Sg = fmaf(dd, 4.0f * p1h * P2h, Sg);       // dPhi
    Sl = fmaf(t * dd, -8.0f * p1h * p1h * P2h, Sl);  // d2Phi
  }
  stTab[c] = St;
  gsTab[c] = (unsigned)__half_as_ushort(__float2half_rn(Sg)) |
             ((unsigned)__half_as_ushort(__float2half_rn(Sl)) << 16);
}

// ---------------------------------------------------------------------------
// Main: 1024 blocks = 32 jobs x 32 rowgroups(16 rows). 512 threads:
// 32 threads per row, each thread owns 16 j's.
// Mode-specialized staging & gathers (E telescoped):
//   DRIFT (l=1..6): stage packed plane (8KB); ONE ds_read_b32 gather/pair
//                   (was ds_read2_b32: 128 bank-accesses -> 64, conflicts ~halve).
//   L0    (l==0)  : stage st + packed (16KB); 2 b32 gathers/pair.
//   EMODE (l==7)  : stage st (8KB); 1 b32 gather/pair.
// DPP reductions on the VALU pipe (round 8). No cross-block sync (rounds
// 1/3/5: L2 maintenance storms + f64 CAS contention always lose).
__global__ __launch_bounds__(512)
void tfl_main12(const float* __restrict__ data, const float* __restrict__ tsnap,
                const float* __restrict__ W1, const float* __restrict__ b1,
                const float* __restrict__ w2, const float* __restrict__ stTab,
                const unsigned* __restrict__ gsTab,
                double* __restrict__ partials) {
  const int jb = blockIdx.x >> 5;
  const int rb = blockIdx.x & 31;
  const bool emode = (jb >= N_STEPS);
  const int m = emode ? (jb - N_STEPS) : jb / (L_DIM - 1);
  const int l = emode ? (L_DIM - 1) : jb % (L_DIM - 1);
  const bool l0 = (!emode && l == 0);
  const float* X = data + (size_t)(m * L_DIM + l) * (N_PART * 2);

  __shared__ __align__(16) float sPl[NCELL * 2];    // 16 KB (mode-dep views)
  __shared__ __align__(16) float Xs[N_PART * 2];    // 4 KB
  __shared__ double sred[8][3];

  const int tid = threadIdx.x;
  if (tid < 256) ((float4*)Xs)[tid] = ((const float4*)X)[tid];
  if (l0) {
    ((float4*)sPl)[tid] = ((const float4*)stTab)[tid];         // st: 8 KB
    ((float4*)sPl)[512 + tid] = ((const float4*)gsTab)[tid];   // gs: 8 KB
  } else if (!emode) {
    ((float4*)sPl)[tid] = ((const float4*)gsTab)[tid];         // gs only
  } else {
    ((float4*)sPl)[tid] = ((const float4*)stTab)[tid];         // st only
  }
  __syncthreads();

  const float* sSt = sPl;                                      // L0 / EMODE
  const unsigned* sGsU = (const unsigned*)(sPl + (l0 ? NCELL : 0));

  const int wv = tid >> 6;
  const int ln = tid & 63;
  const int g = ln & 31;               // j-group id / h id (32 lanes per row)
  const int row = rb * 16 + (tid >> 5);
  const float xi0 = Xs[2 * row], xi1 = Xs[2 * row + 1];
  const float invN = 1.0f / N_PART;
  const float invN2 = invN * invN;
  const float rs0 = __builtin_amdgcn_rsqf(1e-20f);
  const float2* Xs2 = (const float2*)Xs;

  float bJd = 0.f, bLap = 0.f, bE = 0.f;       // this wave's 2-row partials

  if (!emode && !l0) {
    // ------- DRIFT: ONE b32 packed gather, no St, no Vi, 3-var reduce -----
    float aGx = 0.f, aGy = 0.f, aLw = 0.f;
#pragma unroll 4
    for (int kk = 0; kk < 16; ++kk) {
      const int j = g + 32 * kk;
      float2 xj = Xs2[j];
      float dx = xi0 - xj.x, dy = xi1 - xj.y;
      float sq = fmaxf(fmaf(dx, dx, dy * dy), 1e-20f);
      float rs = __builtin_amdgcn_rsqf(sq);
      float r = sq * rs;
      int ki = (int)fmaf(r, TSCALE, 0.5f);
      ki = min(ki, NCELL - 1);
      float2 gs = unpack_gs(sGsU[ki]);
      float tg = gs.x * rs;                     // dPhi / r
      aGx = fmaf(dx, tg, aGx);
      aGy = fmaf(dy, tg, aGy);
      aLw += tg + gs.y;                         // d2Phi + dPhi/r (incl diag)
    }
    float gVx, gVy, lapV;
    {
      float w10 = W1[g], w11 = W1[H_DIM + g], w2h = w2[g];
      float arg = TWO_LOG2E * fmaf(xi0, w10, fmaf(xi1, w11, b1[g]));
      float y = __builtin_amdgcn_exp2f(arg);
      float u = __builtin_amdgcn_rcpf(y + 1.0f);
      float t = fmaf(-2.0f, u, 1.0f);
      float dd = fmaf(-u, u, u);
      float g4 = 4.0f * dd * w2h;
      gVx = g4 * w10;
      gVy = g4 * w11;
      lapV = t * dd * (-8.0f * w2h) * fmaf(w10, w10, w11 * w11);
    }
    float gx = red32(fmaf(aGx, invN, gVx));
    float gy = red32(fmaf(aGy, invN, gVy));
    float lw = red32(fmaf(aLw, invN, lapV));
    float2 gs0 = unpack_gs(sGsU[0]);            // same f16 values loop added
    lw -= fmaf(gs0.x, rs0, gs0.y) * invN;       // remove diagonal lap term
    float cJd = fmaf(gx, gx, gy * gy);
    cJd += __shfl_xor(cJd, 32);
    lw += __shfl_xor(lw, 32);
    bJd = cJd; bLap = lw;
  } else if (l0) {
    // ------- L0: full path (drift + lap + E), 2 b32 gathers ---------------
    float aSt = 0.f, aGx = 0.f, aGy = 0.f, aLw = 0.f;
#pragma unroll 4
    for (int kk = 0; kk < 16; ++kk) {
      const int j = g + 32 * kk;
      float2 xj = Xs2[j];
      float dx = xi0 - xj.x, dy = xi1 - xj.y;
      float sq = fmaxf(fmaf(dx, dx, dy * dy), 1e-20f);
      float rs = __builtin_amdgcn_rsqf(sq);
      float r = sq * rs;
      int ki = (int)fmaf(r, TSCALE, 0.5f);
      ki = min(ki, NCELL - 1);
      float Stv = sSt[ki];
      float2 gs = unpack_gs(sGsU[ki]);
      float tg = gs.x * rs;
      aSt += Stv;
      aGx = fmaf(dx, tg, aGx);
      aGy = fmaf(dy, tg, aGy);
      aLw += tg + gs.y;
    }
    float Vi, gVx, gVy, lapV;
    {
      float w10 = W1[g], w11 = W1[H_DIM + g], w2h = w2[g];
      float arg = TWO_LOG2E * fmaf(xi0, w10, fmaf(xi1, w11, b1[g]));
      float y = __builtin_amdgcn_exp2f(arg);
      float u = __builtin_amdgcn_rcpf(y + 1.0f);
      float t = fmaf(-2.0f, u, 1.0f);
      float dd = fmaf(-u, u, u);
      Vi = t * w2h;
      float g4 = 4.0f * dd * w2h;
      gVx = g4 * w10;
      gVy = g4 * w11;
      lapV = t * dd * (-8.0f * w2h) * fmaf(w10, w10, w11 * w11);
    }
    float eA = red32(fmaf(aSt, invN2, Vi * invN));
    float gx = red32(fmaf(aGx, invN, gVx));
    float gy = red32(fmaf(aGy, invN, gVy));
    float lw = red32(fmaf(aLw, invN, lapV));
    float2 gs0 = unpack_gs(sGsU[0]);
    eA -= sSt[0] * invN2;
    lw -= fmaf(gs0.x, rs0, gs0.y) * invN;
    float cJd = fmaf(gx, gx, gy * gy);
    cJd += __shfl_xor(cJd, 32);
    lw += __shfl_xor(lw, 32);
    eA += __shfl_xor(eA, 32);
    bJd = cJd; bLap = lw; bE = eA;
  } else {
    // ------- EMODE: st plane, 1 b32 gather, 1-var reduce ------------------
    float aSt = 0.f;
#pragma unroll 4
    for (int kk = 0; kk < 16; ++kk) {
      const int j = g + 32 * kk;
      float2 xj = Xs2[j];
      float dx = xi0 - xj.x, dy = xi1 - xj.y;
      float sq = fmaxf(fmaf(dx, dx, dy * dy), 1e-20f);
      float rs = __builtin_amdgcn_rsqf(sq);
      float r = sq * rs;
      int ki = (int)fmaf(r, TSCALE, 0.5f);
      ki = min(ki, NCELL - 1);
      aSt += sSt[ki];
    }
    float Vi;
    {
      float w10 = W1[g], w11 = W1[H_DIM + g], w2h = w2[g];
      float arg = TWO_LOG2E * fmaf(xi0, w10, fmaf(xi1, w11, b1[g]));
      float y = __builtin_amdgcn_exp2f(arg);
      float u = __builtin_amdgcn_rcpf(y + 1.0f);
      float t = fmaf(-2.0f, u, 1.0f);
      Vi = t * w2h;
    }
    float eA = red32(fmaf(aSt, invN2, Vi * invN));
    eA -= sSt[0] * invN2;                       // remove diagonal Phi term
    eA += __shfl_xor(eA, 32);
    bE = eA;
  }

  // ----- per-wave partials -> block partial -> global store -----
  // (32-sums live in DPP-rows 1,3; after the xor-32 combine, lane 16 holds
  //  the wave total)
  if (ln == 16) { sred[wv][0] = bJd; sred[wv][1] = bLap; sred[wv][2] = bE; }
  __syncthreads();
  if (tid == 0) {
    double sJd = 0, sLap = 0, sE = 0;
    for (int w = 0; w < 8; ++w) {
      sJd += sred[w][0]; sLap += sred[w][1]; sE += sred[w][2];
    }
    const double dN = 1.0 / N_PART;
    double j0 = 0.0, j1 = 0.0, j2 = 0.0;
    if (emode) {
      j2 = sE;                                  // +E(m, L-1) telescoped
    } else {
      double dt = (double)(tsnap[l + 1] - tsnap[l]);
      j0 = dt * dN * sJd;                       // J_diss partial
      j1 = dt * 0.01 * dN * sLap;               // J_diff partial
      if (l == 0) j2 = -sE;                     // -E(m, 0) telescoped
    }
    partials[(size_t)blockIdx.x * 3 + 0] = j0;
    partials[(size_t)blockIdx.x * 3 + 1] = j1;
    partials[(size_t)blockIdx.x * 3 + 2] = j2;
  }
}

// ---------------------------------------------------------------------------
// 1 block, 512 threads: each thread sums 2 partial triplets, then a 6-step
// 64-lane shuffle reduce + 8-wave LDS combine (one barrier).
__global__ __launch_bounds__(512)
void tfl_finalize(const double* __restrict__ partials, float* __restrict__ out) {
  __shared__ double sred[8][3];
  const int tid = threadIdx.x;
  const int wv = tid >> 6;
  const int ln = tid & 63;
  const double* pa = partials + (size_t)tid * 3;
  const double* pb = partials + (size_t)(tid + 512) * 3;
  double t0 = pa[0] + pb[0];
  double t1 = pa[1] + pb[1];
  double t2 = pa[2] + pb[2];
#pragma unroll
  for (int sh = 1; sh < 64; sh <<= 1) {
    t0 += __shfl_xor(t0, sh);
    t1 += __shfl_xor(t1, sh);
    t2 += __shfl_xor(t2, sh);
  }
  if (ln == 0) { sred[wv][0] = t0; sred[wv][1] = t1; sred[wv][2] = t2; }
  __syncthreads();
  if (tid == 0) {
    double s0 = 0, s1 = 0, s2 = 0;
    for (int w = 0; w < 8; ++w) {
      s0 += sred[w][0]; s1 += sred[w][1]; s2 += sred[w][2];
    }
    double r = (s0 + s1 - 2.0 * s2) / (double)N_STEPS;
    out[0] = (float)(r * r);
  }
}

// ---------------------------------------------------------------------------
extern "C" void kernel_launch(void* const* d_in, const int* in_sizes, int n_in,
                              void* d_out, int out_size, void* d_ws, size_t ws_size,
                              hipStream_t stream) {
  (void)in_sizes; (void)n_in; (void)out_size; (void)ws_size;
  const float* data  = (const float*)d_in[0];
  const float* tsnap = (const float*)d_in[1];
  const float* W1    = (const float*)d_in[2];
  const float* b1    = (const float*)d_in[3];
  const float* w2    = (const float*)d_in[4];
  // d_in[5] = b2 (cancels in telescoped dE)
  const float* p1    = (const float*)d_in[6];
  const float* pb1   = (const float*)d_in[7];
  const float* p2    = (const float*)d_in[8];
  // d_in[9] = pb2 (cancels in telescoped dE)
  float* stTab = (float*)((char*)d_ws + ST_OFF);
  unsigned* gsTab = (unsigned*)((char*)d_ws + GS_OFF);
  double* partials = (double*)((char*)d_ws + PART_OFF);
  float* out = (float*)d_out;

  hipLaunchKernelGGL(tfl_tabgen, dim3(NCELL / 256), dim3(256), 0, stream,
                     p1, pb1, p2, stTab, gsTab);
  hipLaunchKernelGGL(tfl_main12, dim3(NBLK), dim3(512), 0, stream,
                     data, tsnap, W1, b1, w2, stTab, gsTab, partials);
  hipLaunchKernelGGL(tfl_finalize, dim3(1), dim3(512), 0, stream, partials, out);
}